// Round 23
// baseline (584.636 us; speedup 1.0000x reference)
//
#include <hip/hip_runtime.h>
#include <float.h>

// Sparsemax attention v15: 32 q-rows/wave via mfma_f32_32x32x16_f16.
// B=2,H=16,S=2048,D=64 fp32, temperature 8.
//
// r21/r22: L1-sync and LDS-staging dedupe both lost to sync costs -> reduce
// bytes/wave at the source instead. One 32x32 MFMA tile covers 32 q-rows per
// K-fragment read (vs 16) -> scan traffic halves, ZERO new barriers, r18
// schedule intact. Layout (verified m74/m101): q-row = l&31 (all 16 acc
// elems in one row -> stats reduce = xor32 only), K-col = (r&3)+8(r>>2)+4(l>>5).
//   pass 1: rowmax. pass 2: (s,c)@(max-8) -> t1. pass 3: collect@t1 -> t2.
//   list Michelot from t2 -> exact tau; slot-rewrite p|col; sparse PV in two
//   16-row halves. Overflow -> full-scan Michelot + dense PV (any-data OK).

#define S_LEN 2048
#define DHEAD 64
#define WROWS 32
#define BWAVES 4
#define LCAP 32

typedef _Float16 f16x8 __attribute__((ext_vector_type(8)));
typedef __attribute__((ext_vector_type(16))) float f32x16;

__device__ __forceinline__ unsigned short f2h(float x) {
    return __builtin_bit_cast(unsigned short, (_Float16)x);
}
__device__ __forceinline__ unsigned int pk2h(float lo, float hi) {
    return (unsigned int)f2h(lo) | ((unsigned int)f2h(hi) << 16);
}
__device__ __forceinline__ f16x8 cvt8h(float4 a, float4 b) {
    union { unsigned int u[4]; f16x8 v; } r;
    r.u[0] = pk2h(a.x, a.y); r.u[1] = pk2h(a.z, a.w);
    r.u[2] = pk2h(b.x, b.y); r.u[3] = pk2h(b.z, b.w);
    return r.v;
}

// K fp32 [bh][2048][64] -> 32x32x16 A-operand fragments.
// frag ((bh*64 + ct)*4 + g) lane l holds
//   f16(K[bh][ct*32 + (l&31)][g*16 + (l>>5)*8 + 0..7])
__global__ __launch_bounds__(256)
void kswz32_kernel(const float* __restrict__ K, uint4* __restrict__ dst, int nfrag) {
    int tid = blockIdx.x * 256 + threadIdx.x;
    if (tid >= nfrag) return;
    const int lane = tid & 63;
    const int g    = (tid >> 6) & 3;
    const int ct   = (tid >> 8) & 63;
    const int bh   = tid >> 14;
    const int row  = ct * 32 + (lane & 31);
    const int col  = g * 16 + (lane >> 5) * 8;
    const float* src = K + ((size_t)bh * S_LEN + row) * DHEAD + col;
    float4 a = *reinterpret_cast<const float4*>(src);
    float4 b = *reinterpret_cast<const float4*>(src + 4);
    uint4 o;
    o.x = pk2h(a.x, a.y); o.y = pk2h(a.z, a.w);
    o.z = pk2h(b.x, b.y); o.w = pk2h(b.z, b.w);
    dst[tid] = o;
}

__global__ __launch_bounds__(256, 4)
void spx_main(const float* __restrict__ Q,
              const unsigned short* __restrict__ Ks,
              const float* __restrict__ V,
              float* __restrict__ O)
{
    // [wave][slot][lane]: row r's list = lanes r and r+32 (2 halves).
    // Wave's 8 KB chunk doubles as the fallback p-buffer [32][32].
    __shared__ unsigned int s_pack[BWAVES][LCAP][64];   // 32 KB

    const int t    = threadIdx.x;
    const int widx = t >> 6;
    const int l    = t & 63;
    const int r31  = l & 31;        // this lane's q-row
    const int lh   = l >> 5;        // k-group half / col-half

    int bid = blockIdx.x;
    if (((int)gridDim.x & 7) == 0)
        bid = (bid & 7) * ((int)gridDim.x >> 3) + (bid >> 3);   // XCD swizzle
    const int nrb   = S_LEN / (WROWS * BWAVES);      // 16 row-blocks per bh
    const int bh    = bid / nrb;
    const int row0w = (bid % nrb) * (WROWS * BWAVES) + widx * WROWS;

    const float* Qf = Q + (size_t)bh * S_LEN * DHEAD;
    const unsigned short* KsB = Ks + (size_t)bh * S_LEN * DHEAD;
    const float* Vb = V + (size_t)bh * S_LEN * DHEAD;
    float* Of = O + (size_t)bh * S_LEN * DHEAD;

    // ---- Q^T B-fragments: lane holds Q[row0w+r31][g*16 + lh*8 + j] ----
    f16x8 qfrag[4];
    #pragma unroll
    for (int g = 0; g < 4; ++g) {
        const float* qp = Qf + (size_t)(row0w + r31) * DHEAD + g * 16 + lh * 8;
        qfrag[g] = cvt8h(*reinterpret_cast<const float4*>(qp),
                         *reinterpret_cast<const float4*>(qp + 4));
    }

    // transient score tile (32 cols): acc[r] = S[q=r31][ct*32 + colin(r)],
    // colin(r) = (r&3) + 8*(r>>2) + 4*lh
    #define SCORE_TILE(acc_, ct_) {                                              \
        const unsigned short* kb_ = KsB + (size_t)(ct_) * 2048;                  \
        acc_ = (f32x16){0.f,0.f,0.f,0.f,0.f,0.f,0.f,0.f,                         \
                        0.f,0.f,0.f,0.f,0.f,0.f,0.f,0.f};                        \
        _Pragma("unroll")                                                        \
        for (int g_ = 0; g_ < 4; ++g_) {                                         \
            f16x8 af_ = *reinterpret_cast<const f16x8*>(kb_ + g_ * 512 + l * 8); \
            acc_ = __builtin_amdgcn_mfma_f32_32x32x16_f16(af_, qfrag[g_], acc_, 0, 0, 0); \
        }                                                                        \
    }

    // ---- pass 1: row max ----
    float mx = -FLT_MAX;
    #pragma unroll 2
    for (int ct = 0; ct < S_LEN / 32; ++ct) {
        f32x16 a;
        SCORE_TILE(a, ct);
        #pragma unroll
        for (int r = 0; r < 16; ++r) mx = fmaxf(mx, a[r]);
    }
    mx = fmaxf(mx, __shfl_xor(mx, 32));

    // ---- pass 2: (sum,count)@(max-8) -> t1 ----
    float t1;
    {
        const float thr0 = mx - 8.f;
        float s2 = 0.f, c2 = 0.f;
        #pragma unroll 2
        for (int ct = 0; ct < S_LEN / 32; ++ct) {
            f32x16 a;
            SCORE_TILE(a, ct);
            #pragma unroll
            for (int r = 0; r < 16; ++r) {
                const bool in = a[r] > thr0;
                s2 += in ? a[r] : 0.f;
                c2 += in ? 1.f : 0.f;
            }
        }
        s2 += __shfl_xor(s2, 32);
        c2 += __shfl_xor(c2, 32);
        t1 = (s2 - 8.f) / c2;            // c2 >= 1 (max itself qualifies)
    }

    // ---- pass 3: collect {s > t1} + (sum,count)@t1 -> t2 ----
    int own = 0;
    float t2;
    {
        float s3 = 0.f, c3 = 0.f;
        const int cb = 4 * lh;           // col-in-tile base for this half
        #pragma unroll 2
        for (int ct = 0; ct < S_LEN / 32; ++ct) {
            f32x16 a;
            SCORE_TILE(a, ct);
            #pragma unroll
            for (int r = 0; r < 16; ++r) {
                const float v = a[r];
                if (v > t1) {
                    s3 += v; c3 += 1.f;
                    if (own < LCAP) {
                        const unsigned int pk =
                            (__builtin_bit_cast(unsigned int, v) & 0xFFFFF800u)
                            | (unsigned int)(ct * 32 + (r & 3) + 8 * (r >> 2) + cb);
                        s_pack[widx][own][l] = pk;
                    }
                    ++own;
                }
            }
        }
        for (int i = (own < LCAP ? own : LCAP); i < LCAP; ++i)
            s_pack[widx][i][l] = 0xFF800000u;     // -inf sentinel, col 0
        s3 += __shfl_xor(s3, 32);
        c3 += __shfl_xor(c3, 32);
        t2 = (s3 - 8.f) / c3;            // c3 >= 1 (max > t1 always)
    }

    // wave-wide max slot count (bounds the PV loop)
    int maxc = own < LCAP ? own : LCAP;
    #pragma unroll
    for (int o = 1; o < 64; o <<= 1) {
        const int m2 = __shfl_xor(maxc, o);
        maxc = m2 > maxc ? m2 : maxc;
    }

    const bool ovf = __any(own > LCAP);
    float tauF;
    if (!ovf) {
        // ---- in-wave list Michelot from t2 (1-2 steps to fixpoint) ----
        float cand[LCAP];
        #pragma unroll
        for (int s = 0; s < LCAP; ++s)
            cand[s] = __builtin_bit_cast(float, s_pack[widx][s][l] & 0xFFFFF800u);
        float tv = t2;
        int cprev = -1;
        for (int it = 0; it < 20; ++it) {
            float s = 0.f, c = 0.f;
            #pragma unroll
            for (int q = 0; q < LCAP; ++q) {
                const bool in = cand[q] > tv;
                s += in ? cand[q] : 0.f;
                c += in ? 1.f : 0.f;
            }
            s += __shfl_xor(s, 32);
            c += __shfl_xor(c, 32);
            tv = (s - 8.f) / c;
            const int C = (int)c;
            const bool done = (C == cprev);
            cprev = C;
            if (__all(done ? 1 : 0)) break;   // fixpoint on all rows: exact
        }
        tauF = tv;

        // rewrite own slots: p = max(val - tau, 0) | col (sentinel -> p=0)
        #pragma unroll
        for (int s = 0; s < LCAP; ++s) {
            const unsigned int pk = s_pack[widx][s][l];
            const float p = fmaxf(__builtin_bit_cast(float, pk & 0xFFFFF800u) - tauF, 0.f);
            s_pack[widx][s][l] =
                (__builtin_bit_cast(unsigned int, p) & 0xFFFFF800u) | (pk & 0x7FFu);
        }

        // ---- sparse PV: two 16-row halves, 64 indep chains per slot ----
        const float* Vl = Vb + l;
        #pragma unroll
        for (int rt = 0; rt < 2; ++rt) {
            float oac[16];
            #pragma unroll
            for (int r = 0; r < 16; ++r) oac[r] = 0.f;
            for (int i = 0; i < maxc; ++i) {
                #pragma unroll
                for (int r = 0; r < 16; ++r) {
                    const int row = rt * 16 + r;
                    const unsigned int p0 = s_pack[widx][i][row];       // bcast
                    const unsigned int p1 = s_pack[widx][i][row + 32];  // bcast
                    oac[r] = fmaf(__builtin_bit_cast(float, p0 & 0xFFFFF800u),
                                  Vl[(size_t)(p0 & 0x7FFu) * DHEAD], oac[r]);
                    oac[r] = fmaf(__builtin_bit_cast(float, p1 & 0xFFFFF800u),
                                  Vl[(size_t)(p1 & 0x7FFu) * DHEAD], oac[r]);
                }
            }
            #pragma unroll
            for (int r = 0; r < 16; ++r)
                Of[(size_t)(row0w + rt * 16 + r) * DHEAD + l] = oac[r] * 0.125f;
        }
    } else {
        // ---- fallback: full-scan Michelot from t2 + dense PV ----
        float tv = t2;
        int cprev = -1;
        for (int it = 0; it < 12; ++it) {
            float s = 0.f, c = 0.f;
            #pragma unroll 2
            for (int ct = 0; ct < S_LEN / 32; ++ct) {
                f32x16 a;
                SCORE_TILE(a, ct);
                #pragma unroll
                for (int r = 0; r < 16; ++r) {
                    const bool in = a[r] > tv;
                    s += in ? a[r] : 0.f;
                    c += in ? 1.f : 0.f;
                }
            }
            s += __shfl_xor(s, 32);
            c += __shfl_xor(c, 32);
            tv = (s - 8.f) / c;
            const int C = (int)c;
            const bool done = (C == cprev);
            cprev = C;
            if (__all(done ? 1 : 0)) break;
        }
        tauF = tv;

        // dense PV: per 32-col tile, p -> wave's own 8 KB LDS [32][32]
        float* p_lds = reinterpret_cast<float*>(&s_pack[widx][0][0]);
        float ofb[32];
        #pragma unroll
        for (int r = 0; r < 32; ++r) ofb[r] = 0.f;
        const int cb = 4 * lh;
        for (int ct = 0; ct < S_LEN / 32; ++ct) {
            f32x16 a;
            SCORE_TILE(a, ct);
            #pragma unroll
            for (int r = 0; r < 16; ++r)
                p_lds[r31 * 32 + (r & 3) + 8 * (r >> 2) + cb] = fmaxf(a[r] - tauF, 0.f);
            for (int c2 = 0; c2 < 32; ++c2) {
                const float vv = Vb[(size_t)(ct * 32 + c2) * DHEAD + l];
                #pragma unroll
                for (int r = 0; r < 32; ++r)
                    ofb[r] += p_lds[r * 32 + c2] * vv;
            }
        }
        #pragma unroll
        for (int r = 0; r < 32; ++r)
            Of[(size_t)(row0w + r) * DHEAD + l] = ofb[r] * 0.125f;
    }
    #undef SCORE_TILE
}

extern "C" void kernel_launch(void* const* d_in, const int* in_sizes, int n_in,
                              void* d_out, int out_size, void* d_ws, size_t ws_size,
                              hipStream_t stream) {
    const float* q = (const float*)d_in[0];
    const float* k = (const float*)d_in[1];
    const float* v = (const float*)d_in[2];
    float* out = (float*)d_out;

    const int nElem = in_sizes[0];                    // B*H*S*D = 4194304
    const int BH    = nElem / (S_LEN * DHEAD);

    unsigned short* ks = (unsigned short*)d_ws;
    const int nfrag = nElem / 8;
    kswz32_kernel<<<(nfrag + 255) / 256, 256, 0, stream>>>(k, (uint4*)ks, nfrag);

    const int grid = BH * (S_LEN / (WROWS * BWAVES)); // 512 blocks
    spx_main<<<grid, 256, 0, stream>>>(q, ks, v, out);
}

// Round 24
// 204.848 us; speedup vs baseline: 2.8540x; 2.8540x over previous
//
#include <hip/hip_runtime.h>
#include <float.h>

// Sparsemax attention v16 = r20 (2-scan fused collect) + slot-rewrite p|col
// + wave-uniform zero-skip PV.  B=2,H=16,S=2048,D=64 fp32, temperature 8.
//
// r20 lost to r18 (181 vs 158) because the loose max-8 list made branchless
// PV load V for ~75% junk slots. This keeps r20's 2-scan structure and
// removes the junk cost: after tau, slots are rewritten as packed p|col
// (p=0 for sub-tau/sentinel), and PV skips p==0 via a wave-uniform branch
// (slot words are lane-broadcast). V loads = true support count only.
//   pass 1: rowmax.
//   pass 2: capless (s,c)@(max-8) -> t1 + capped collect@(max-8), LCAP=32.
//   no overflow: list Michelot from t1 -> exact tau (pass 3 skipped).
//   overflow: recollect@t1 -> t2 (tight); still-overflow: full-scan
//   Michelot + dense PV (any-data correct).

#define S_LEN 2048
#define DHEAD 64
#define WROWS 16
#define BWAVES 4
#define LCAP 32

typedef _Float16 f16x8 __attribute__((ext_vector_type(8)));
typedef __attribute__((ext_vector_type(4))) float f32x4;

__device__ __forceinline__ unsigned short f2h(float x) {
    return __builtin_bit_cast(unsigned short, (_Float16)x);
}
__device__ __forceinline__ unsigned int pk2h(float lo, float hi) {
    return (unsigned int)f2h(lo) | ((unsigned int)f2h(hi) << 16);
}
__device__ __forceinline__ f16x8 cvt8h(float4 a, float4 b) {
    union { unsigned int u[4]; f16x8 v; } r;
    r.u[0] = pk2h(a.x, a.y); r.u[1] = pk2h(a.z, a.w);
    r.u[2] = pk2h(b.x, b.y); r.u[3] = pk2h(b.z, b.w);
    return r.v;
}

// K fp32 [bh][2048][64] -> fragment-contiguous fp16 (r14-proven layout).
__global__ __launch_bounds__(256)
void kswz_kernel(const float* __restrict__ K, uint4* __restrict__ dst, int nfrag) {
    int tid = blockIdx.x * 256 + threadIdx.x;
    if (tid >= nfrag) return;
    const int lane = tid & 63;
    const int grp  = (tid >> 6) & 1;
    const int ct   = (tid >> 7) & 127;
    const int bh   = tid >> 14;
    const int row  = ct * 16 + (lane & 15);
    const int col  = grp * 32 + (lane >> 4) * 8;
    const float* src = K + ((size_t)bh * S_LEN + row) * DHEAD + col;
    float4 a = *reinterpret_cast<const float4*>(src);
    float4 b = *reinterpret_cast<const float4*>(src + 4);
    uint4 o;
    o.x = pk2h(a.x, a.y); o.y = pk2h(a.z, a.w);
    o.z = pk2h(b.x, b.y); o.w = pk2h(b.z, b.w);
    dst[tid] = o;
}

__global__ __launch_bounds__(256, 4)
void spx_main(const float* __restrict__ Q,
              const unsigned short* __restrict__ Ks,
              const float* __restrict__ V,
              float* __restrict__ O)
{
    // [wave][slot][lane]; wave's 8 KB chunk doubles as fallback p-buffer.
    __shared__ unsigned int s_pack[BWAVES][LCAP][64];   // 32 KB

    const int t    = threadIdx.x;
    const int widx = t >> 6;
    const int l    = t & 63;
    const int lm   = l & 15;
    const int lk   = l >> 4;

    int bid = blockIdx.x;
    if (((int)gridDim.x & 7) == 0)
        bid = (bid & 7) * ((int)gridDim.x >> 3) + (bid >> 3);   // XCD swizzle
    const int nrb   = S_LEN / (WROWS * BWAVES);      // 32 row-blocks per bh
    const int bh    = bid / nrb;
    const int row0w = (bid % nrb) * (WROWS * BWAVES) + widx * WROWS;

    const float* Qf = Q + (size_t)bh * S_LEN * DHEAD;
    const unsigned short* KsB = Ks + (size_t)bh * S_LEN * DHEAD;
    const float* Vb = V + (size_t)bh * S_LEN * DHEAD;
    float* Of = O + (size_t)bh * S_LEN * DHEAD;

    // ---- Q^T B-fragments ----
    f16x8 qfrag[2];
    #pragma unroll
    for (int kp = 0; kp < 2; ++kp) {
        const float* qp = Qf + (size_t)(row0w + lm) * DHEAD + kp * 32 + lk * 8;
        qfrag[kp] = cvt8h(*reinterpret_cast<const float4*>(qp),
                          *reinterpret_cast<const float4*>(qp + 4));
    }

    // transient score tile: S[qrow=lm][ct*16 + lk*4 + e], contiguous frags
    #define SCORE_TILE(a_, ct_)                                                  \
        {                                                                        \
            const unsigned short* kb_ = KsB + (size_t)(ct_) * 1024;              \
            f16x8 k0_ = *reinterpret_cast<const f16x8*>(kb_ + l * 8);            \
            f16x8 k1_ = *reinterpret_cast<const f16x8*>(kb_ + 512 + l * 8);      \
            a_ = (f32x4){0.f, 0.f, 0.f, 0.f};                                    \
            a_ = __builtin_amdgcn_mfma_f32_16x16x32_f16(k0_, qfrag[0], a_, 0, 0, 0); \
            a_ = __builtin_amdgcn_mfma_f32_16x16x32_f16(k1_, qfrag[1], a_, 0, 0, 0); \
        }

    // ---- pass 1: row max ----
    float mx = -FLT_MAX;
    #pragma unroll 8
    for (int ct = 0; ct < S_LEN / 16; ++ct) {
        f32x4 a;
        SCORE_TILE(a, ct);
        mx = fmaxf(mx, fmaxf(fmaxf(a[0], a[1]), fmaxf(a[2], a[3])));
    }
    mx = fmaxf(mx, __shfl_xor(mx, 16));
    mx = fmaxf(mx, __shfl_xor(mx, 32));

    // ---- pass 2: capless (sum,count)@(max-8) -> t1  +  capped collect ----
    int own = 0;
    float startT;
    {
        const float thr0 = mx - 8.f;
        float lsum = 0.f;
        #pragma unroll 2
        for (int ct = 0; ct < S_LEN / 16; ++ct) {
            f32x4 a;
            SCORE_TILE(a, ct);
            #pragma unroll
            for (int e = 0; e < 4; ++e) {
                const float v = a[e];
                if (v > thr0) {
                    lsum += v;
                    if (own < LCAP) {
                        const unsigned int pk =
                            (__builtin_bit_cast(unsigned int, v) & 0xFFFFF800u)
                            | (unsigned int)(ct * 16 + lk * 4 + e);
                        s_pack[widx][own][l] = pk;
                    }
                    ++own;
                }
            }
        }
        for (int i = (own < LCAP ? own : LCAP); i < LCAP; ++i)
            s_pack[widx][i][l] = 0xFF800000u;     // -inf sentinel, col 0
        float s2 = lsum, c2 = (float)own;
        s2 += __shfl_xor(s2, 16); c2 += __shfl_xor(c2, 16);
        s2 += __shfl_xor(s2, 32); c2 += __shfl_xor(c2, 32);
        startT = (s2 - 8.f) / c2;        // t1, exact Michelot iterate
    }

    bool ovf = __any(own > LCAP);
    if (ovf) {
        // ---- pass 3 (minority): recollect @ t1, (sum,count)@t1 -> t2 ----
        const float th = startT;
        own = 0;
        float s3 = 0.f, c3 = 0.f;
        #pragma unroll 2
        for (int ct = 0; ct < S_LEN / 16; ++ct) {
            f32x4 a;
            SCORE_TILE(a, ct);
            #pragma unroll
            for (int e = 0; e < 4; ++e) {
                const float v = a[e];
                if (v > th) {
                    s3 += v; c3 += 1.f;
                    if (own < LCAP) {
                        const unsigned int pk =
                            (__builtin_bit_cast(unsigned int, v) & 0xFFFFF800u)
                            | (unsigned int)(ct * 16 + lk * 4 + e);
                        s_pack[widx][own][l] = pk;
                    }
                    ++own;
                }
            }
        }
        for (int i = (own < LCAP ? own : LCAP); i < LCAP; ++i)
            s_pack[widx][i][l] = 0xFF800000u;
        s3 += __shfl_xor(s3, 16); c3 += __shfl_xor(c3, 16);
        s3 += __shfl_xor(s3, 32); c3 += __shfl_xor(c3, 32);
        startT = (s3 - 8.f) / c3;        // t2, exact
        ovf = __any(own > LCAP);
    }

    // wave-wide max slot count (bounds the PV loop)
    int maxc = own < LCAP ? own : LCAP;
    #pragma unroll
    for (int o = 1; o < 64; o <<= 1) {
        const int m2 = __shfl_xor(maxc, o);
        maxc = m2 > maxc ? m2 : maxc;
    }

    float tauF;
    if (!ovf) {
        // ---- in-wave list Michelot from startT ----
        float cand[LCAP];
        #pragma unroll
        for (int s = 0; s < LCAP; ++s)
            cand[s] = __builtin_bit_cast(float, s_pack[widx][s][l] & 0xFFFFF800u);
        float tv = startT;
        int cprev = -1;
        for (int it = 0; it < 20; ++it) {
            float s = 0.f, c = 0.f;
            #pragma unroll
            for (int q = 0; q < LCAP; ++q) {
                const bool in = cand[q] > tv;
                s += in ? cand[q] : 0.f;
                c += in ? 1.f : 0.f;
            }
            s += __shfl_xor(s, 16); c += __shfl_xor(c, 16);
            s += __shfl_xor(s, 32); c += __shfl_xor(c, 32);
            tv = (s - 8.f) / c;
            const int C = (int)c;
            const bool done = (C == cprev);
            cprev = C;
            if (__all(done ? 1 : 0)) break;   // fixpoint on all rows: exact
        }
        tauF = tv;

        // rewrite own slots: p = max(val - tau, 0) packed with col
        // (sub-tau and sentinel entries become exactly 0 -> PV skips them)
        #pragma unroll
        for (int s = 0; s < LCAP; ++s) {
            const unsigned int pk = s_pack[widx][s][l];
            const float val = __builtin_bit_cast(float, pk & 0xFFFFF800u);
            const float p = fmaxf(val - tauF, 0.f);
            s_pack[widx][s][l] =
                (__builtin_bit_cast(unsigned int, p) & 0xFFFFF800u)
                | (pk & 0x7FFu);
        }

        // ---- sparse PV with wave-uniform zero-skip (loads = support only) ----
        float oac[WROWS];
        #pragma unroll
        for (int r = 0; r < WROWS; ++r) oac[r] = 0.f;
        const float* Vl = Vb + l;

        for (int i = 0; i < maxc; ++i) {
            #pragma unroll
            for (int r = 0; r < WROWS; ++r) {
                #pragma unroll
                for (int j = 0; j < 4; ++j) {
                    const unsigned int pk = s_pack[widx][i][r + 16 * j]; // bcast
                    if (pk & 0xFFFFF800u) {           // uniform: skip p == 0
                        const float p =
                            __builtin_bit_cast(float, pk & 0xFFFFF800u);
                        oac[r] = fmaf(p, Vl[(size_t)(pk & 0x7FFu) * DHEAD],
                                      oac[r]);
                    }
                }
            }
        }
        #pragma unroll
        for (int r = 0; r < WROWS; ++r)
            Of[(size_t)(row0w + r) * DHEAD + l] = oac[r] * 0.125f;
    } else {
        // ---- fallback: full-scan Michelot from startT + dense PV ----
        float tv = startT;
        int cprev = -1;
        for (int it = 0; it < 12; ++it) {
            float s = 0.f, c = 0.f;
            #pragma unroll 4
            for (int ct = 0; ct < S_LEN / 16; ++ct) {
                f32x4 a;
                SCORE_TILE(a, ct);
                #pragma unroll
                for (int e = 0; e < 4; ++e) {
                    const bool in = a[e] > tv;
                    s += in ? a[e] : 0.f;
                    c += in ? 1.f : 0.f;
                }
            }
            s += __shfl_xor(s, 16); c += __shfl_xor(c, 16);
            s += __shfl_xor(s, 32); c += __shfl_xor(c, 32);
            tv = (s - 8.f) / c;
            const int C = (int)c;
            const bool done = (C == cprev);
            cprev = C;
            if (__all(done ? 1 : 0)) break;
        }
        tauF = tv;

        // dense chunked PV via this wave's own 8 KB LDS chunk as [16][128]
        float* p_lds = reinterpret_cast<float*>(&s_pack[widx][0][0]);
        float ofb[WROWS];
        #pragma unroll
        for (int r = 0; r < WROWS; ++r) ofb[r] = 0.f;
        for (int cc = 0; cc < 16; ++cc) {
            #pragma unroll
            for (int tt = 0; tt < 8; ++tt) {
                f32x4 a;
                SCORE_TILE(a, cc * 8 + tt);
                #pragma unroll
                for (int e = 0; e < 4; ++e)
                    p_lds[lm * 128 + tt * 16 + lk * 4 + e] = fmaxf(a[e] - tauF, 0.f);
            }
            for (int c2 = 0; c2 < 128; ++c2) {
                const float vv = Vb[(size_t)(cc * 128 + c2) * DHEAD + l];
                #pragma unroll
                for (int r = 0; r < WROWS; ++r)
                    ofb[r] += p_lds[r * 128 + c2] * vv;
            }
        }
        #pragma unroll
        for (int r = 0; r < WROWS; ++r)
            Of[(size_t)(row0w + r) * DHEAD + l] = ofb[r] * 0.125f;
    }
    #undef SCORE_TILE
}

extern "C" void kernel_launch(void* const* d_in, const int* in_sizes, int n_in,
                              void* d_out, int out_size, void* d_ws, size_t ws_size,
                              hipStream_t stream) {
    const float* q = (const float*)d_in[0];
    const float* k = (const float*)d_in[1];
    const float* v = (const float*)d_in[2];
    float* out = (float*)d_out;

    const int nElem = in_sizes[0];                    // B*H*S*D = 4194304
    const int BH    = nElem / (S_LEN * DHEAD);

    unsigned short* ks = (unsigned short*)d_ws;
    const int nfrag = nElem / 8;
    kswz_kernel<<<(nfrag + 255) / 256, 256, 0, stream>>>(k, (uint4*)ks, nfrag);

    const int grid = BH * (S_LEN / (WROWS * BWAVES)); // 1024 blocks
    spx_main<<<grid, 256, 0, stream>>>(q, ks, v, out);
}

// Round 25
// 144.270 us; speedup vs baseline: 4.0524x; 1.4199x over previous
//
#include <hip/hip_runtime.h>
#include <float.h>

// Sparsemax attention v17 = r18 with scan 2 replaced by FREE fixed-threshold
// g-probes folded into pass 1.  B=2,H=16,S=2048,D=64 fp32, temperature 8.
//
// Statistics: raw scores ~ N(0,64); tau* solves sum(s-tau)+ = 8 (raw), which
// pins tau* ~ 23 with tiny variance. Pass 1 accumulates G(thr)=sum(s-thr)+,
// C(thr) at fixed raw thresholds {21,16}. EXACT validity: G(thr)>=8 <=>
// thr<=tau* (any data). Per row: highest valid tier -> one exact Michelot
// iterate t1 = thr+(G-8)/C in [thr,tau*] (as tight as r18's dedicated scan).
//   pass 1: rowmax + G/C probes -> per-row t1        [1 scan]
//   pass 2: collect@t1 + capless (s,c)@t1 -> t2      [1 scan]
//   list Michelot from t2 -> exact tau; branchless sparse PV.
// Safety (any-data correct): no valid tier -> extra (s,c)@(max-8) scan;
// cap overflow -> recollect@t2; still-overflow -> full-scan Michelot +
// dense PV. All r18-verbatim machinery.

#define S_LEN 2048
#define DHEAD 64
#define WROWS 16
#define BWAVES 4
#define LCAP 32
#define THR_A 21.0f
#define THR_B 16.0f

typedef _Float16 f16x8 __attribute__((ext_vector_type(8)));
typedef __attribute__((ext_vector_type(4))) float f32x4;

__device__ __forceinline__ unsigned short f2h(float x) {
    return __builtin_bit_cast(unsigned short, (_Float16)x);
}
__device__ __forceinline__ unsigned int pk2h(float lo, float hi) {
    return (unsigned int)f2h(lo) | ((unsigned int)f2h(hi) << 16);
}
__device__ __forceinline__ f16x8 cvt8h(float4 a, float4 b) {
    union { unsigned int u[4]; f16x8 v; } r;
    r.u[0] = pk2h(a.x, a.y); r.u[1] = pk2h(a.z, a.w);
    r.u[2] = pk2h(b.x, b.y); r.u[3] = pk2h(b.z, b.w);
    return r.v;
}

// K fp32 [bh][2048][64] -> fragment-contiguous fp16 (r14-proven layout).
__global__ __launch_bounds__(256)
void kswz_kernel(const float* __restrict__ K, uint4* __restrict__ dst, int nfrag) {
    int tid = blockIdx.x * 256 + threadIdx.x;
    if (tid >= nfrag) return;
    const int lane = tid & 63;
    const int grp  = (tid >> 6) & 1;
    const int ct   = (tid >> 7) & 127;
    const int bh   = tid >> 14;
    const int row  = ct * 16 + (lane & 15);
    const int col  = grp * 32 + (lane >> 4) * 8;
    const float* src = K + ((size_t)bh * S_LEN + row) * DHEAD + col;
    float4 a = *reinterpret_cast<const float4*>(src);
    float4 b = *reinterpret_cast<const float4*>(src + 4);
    uint4 o;
    o.x = pk2h(a.x, a.y); o.y = pk2h(a.z, a.w);
    o.z = pk2h(b.x, b.y); o.w = pk2h(b.z, b.w);
    dst[tid] = o;
}

__global__ __launch_bounds__(256, 4)
void spx_main(const float* __restrict__ Q,
              const unsigned short* __restrict__ Ks,
              const float* __restrict__ V,
              float* __restrict__ O)
{
    // [wave][slot][lane]; wave's 8 KB chunk doubles as fallback p-buffer.
    __shared__ unsigned int s_pack[BWAVES][LCAP][64];   // 32 KB

    const int t    = threadIdx.x;
    const int widx = t >> 6;
    const int l    = t & 63;
    const int lm   = l & 15;
    const int lk   = l >> 4;

    int bid = blockIdx.x;
    if (((int)gridDim.x & 7) == 0)
        bid = (bid & 7) * ((int)gridDim.x >> 3) + (bid >> 3);   // XCD swizzle
    const int nrb   = S_LEN / (WROWS * BWAVES);      // 32 row-blocks per bh
    const int bh    = bid / nrb;
    const int row0w = (bid % nrb) * (WROWS * BWAVES) + widx * WROWS;

    const float* Qf = Q + (size_t)bh * S_LEN * DHEAD;
    const unsigned short* KsB = Ks + (size_t)bh * S_LEN * DHEAD;
    const float* Vb = V + (size_t)bh * S_LEN * DHEAD;
    float* Of = O + (size_t)bh * S_LEN * DHEAD;

    // ---- Q^T B-fragments ----
    f16x8 qfrag[2];
    #pragma unroll
    for (int kp = 0; kp < 2; ++kp) {
        const float* qp = Qf + (size_t)(row0w + lm) * DHEAD + kp * 32 + lk * 8;
        qfrag[kp] = cvt8h(*reinterpret_cast<const float4*>(qp),
                          *reinterpret_cast<const float4*>(qp + 4));
    }

    // transient score tile: S[qrow=lm][ct*16 + lk*4 + e], contiguous frags
    #define SCORE_TILE(a_, ct_)                                                  \
        {                                                                        \
            const unsigned short* kb_ = KsB + (size_t)(ct_) * 1024;              \
            f16x8 k0_ = *reinterpret_cast<const f16x8*>(kb_ + l * 8);            \
            f16x8 k1_ = *reinterpret_cast<const f16x8*>(kb_ + 512 + l * 8);      \
            a_ = (f32x4){0.f, 0.f, 0.f, 0.f};                                    \
            a_ = __builtin_amdgcn_mfma_f32_16x16x32_f16(k0_, qfrag[0], a_, 0, 0, 0); \
            a_ = __builtin_amdgcn_mfma_f32_16x16x32_f16(k1_, qfrag[1], a_, 0, 0, 0); \
        }

    // ---- pass 1: row max + g-probes at fixed thresholds {21, 16} ----
    float mx = -FLT_MAX;
    float gA = 0.f, cA = 0.f, gB = 0.f, cB = 0.f;
    #pragma unroll 4
    for (int ct = 0; ct < S_LEN / 16; ++ct) {
        f32x4 a;
        SCORE_TILE(a, ct);
        #pragma unroll
        for (int e = 0; e < 4; ++e) {
            const float v = a[e];
            mx = fmaxf(mx, v);
            const float dA = v - THR_A;
            const float dB = v - THR_B;
            gA += fmaxf(dA, 0.f);
            gB += fmaxf(dB, 0.f);
            cA += (dA > 0.f) ? 1.f : 0.f;
            cB += (dB > 0.f) ? 1.f : 0.f;
        }
    }
    mx = fmaxf(mx, __shfl_xor(mx, 16));
    mx = fmaxf(mx, __shfl_xor(mx, 32));
    gA += __shfl_xor(gA, 16); gA += __shfl_xor(gA, 32);
    cA += __shfl_xor(cA, 16); cA += __shfl_xor(cA, 32);
    gB += __shfl_xor(gB, 16); gB += __shfl_xor(gB, 32);
    cB += __shfl_xor(cB, 16); cB += __shfl_xor(cB, 32);

    // per-row start: highest valid tier's exact Michelot iterate
    // validity: g(thr) = G - 8 >= 0  <=>  thr <= tau*   (exact, any data)
    float t1;
    bool rowvalid;
    if (gA >= 8.f) {
        t1 = THR_A + (gA - 8.f) / cA;
        rowvalid = true;
    } else if (gB >= 8.f) {
        t1 = THR_B + (gB - 8.f) / cB;
        rowvalid = true;
    } else {
        t1 = mx - 8.f;                  // placeholder; refined below
        rowvalid = false;
    }

    if (!__all(rowvalid ? 1 : 0)) {
        // ---- safety scan (any-data correctness; ~never for Gaussian):
        //      capless (sum,count)@(max-8) -> exact iterate, all rows ----
        const float thr0 = mx - 8.f;
        float s2 = 0.f, c2 = 0.f;
        #pragma unroll 4
        for (int ct = 0; ct < S_LEN / 16; ++ct) {
            f32x4 a;
            SCORE_TILE(a, ct);
            #pragma unroll
            for (int e = 0; e < 4; ++e) {
                const bool in = a[e] > thr0;
                s2 += in ? a[e] : 0.f;
                c2 += in ? 1.f : 0.f;
            }
        }
        s2 += __shfl_xor(s2, 16); c2 += __shfl_xor(c2, 16);
        s2 += __shfl_xor(s2, 32); c2 += __shfl_xor(c2, 32);
        t1 = (s2 - 8.f) / c2;           // exact iterate; c2 >= 1
    }

    // ---- pass 2: collect {s > t1} + capless (sum,count)@t1 -> t2 ----
    int own = 0;
    float t2;
    {
        float s3 = 0.f, c3 = 0.f;
        #pragma unroll 2
        for (int ct = 0; ct < S_LEN / 16; ++ct) {
            f32x4 a;
            SCORE_TILE(a, ct);
            #pragma unroll
            for (int e = 0; e < 4; ++e) {
                const float v = a[e];
                if (v > t1) {
                    s3 += v; c3 += 1.f;
                    if (own < LCAP) {
                        const unsigned int pk =
                            (__builtin_bit_cast(unsigned int, v) & 0xFFFFF800u)
                            | (unsigned int)(ct * 16 + lk * 4 + e);
                        s_pack[widx][own][l] = pk;
                    }
                    ++own;
                }
            }
        }
        // sentinel-pad (-inf packed, col 0)
        for (int i = (own < LCAP ? own : LCAP); i < LCAP; ++i)
            s_pack[widx][i][l] = 0xFF800000u;
        s3 += __shfl_xor(s3, 16); c3 += __shfl_xor(c3, 16);
        s3 += __shfl_xor(s3, 32); c3 += __shfl_xor(c3, 32);
        t2 = (s3 - 8.f) / c3;            // c3 >= 1 (max > t1 always)
    }

    // wave-wide max slot count (bounds the PV loop)
    int maxc = own < LCAP ? own : LCAP;
    #pragma unroll
    for (int o = 1; o < 64; o <<= 1) {
        const int m2 = __shfl_xor(maxc, o);
        maxc = m2 > maxc ? m2 : maxc;
    }

    const bool ovf = __any(own > LCAP);
    float tauF;
    if (!ovf) {
        // ---- in-wave list Michelot from t2 (1-2 steps to fixpoint) ----
        float cand[LCAP];
        #pragma unroll
        for (int s = 0; s < LCAP; ++s)
            cand[s] = __builtin_bit_cast(float, s_pack[widx][s][l] & 0xFFFFF800u);
        float tv = t2;
        int cprev = -1;
        for (int it = 0; it < 20; ++it) {
            float s = 0.f, c = 0.f;
            #pragma unroll
            for (int q = 0; q < LCAP; ++q) {
                const bool in = cand[q] > tv;
                s += in ? cand[q] : 0.f;
                c += in ? 1.f : 0.f;
            }
            s += __shfl_xor(s, 16); c += __shfl_xor(c, 16);
            s += __shfl_xor(s, 32); c += __shfl_xor(c, 32);
            tv = (s - 8.f) / c;
            const int C = (int)c;
            const bool done = (C == cprev);
            cprev = C;
            if (__all(done ? 1 : 0)) break;   // fixpoint on all rows: exact
        }
        tauF = tv;

        // ---- branchless interleaved sparse PV (r17/r18-proven) ----
        float tr[WROWS];
        #pragma unroll
        for (int r = 0; r < WROWS; ++r) tr[r] = __shfl(tauF, r);
        float oac[WROWS];
        #pragma unroll
        for (int r = 0; r < WROWS; ++r) oac[r] = 0.f;
        const float* Vl = Vb + l;

        for (int i = 0; i < maxc; ++i) {
            #pragma unroll
            for (int r = 0; r < WROWS; ++r) {
                #pragma unroll
                for (int j = 0; j < 4; ++j) {
                    const unsigned int pk = s_pack[widx][i][r + 16 * j]; // bcast
                    const float val =
                        __builtin_bit_cast(float, pk & 0xFFFFF800u);
                    const float pp = fmaxf(val - tr[r], 0.f);  // 0 for sentinel
                    const int col = (int)(pk & 0x7FFu);
                    oac[r] = fmaf(pp, Vl[(size_t)col * DHEAD], oac[r]);
                }
            }
        }
        #pragma unroll
        for (int r = 0; r < WROWS; ++r)
            Of[(size_t)(row0w + r) * DHEAD + l] = oac[r] * 0.125f;
    } else {
        // ---- fallback: full-scan Michelot from t2 (cheap) + dense PV ----
        float tv = t2;
        int cprev = -1;
        for (int it = 0; it < 12; ++it) {
            float s = 0.f, c = 0.f;
            #pragma unroll 4
            for (int ct = 0; ct < S_LEN / 16; ++ct) {
                f32x4 a;
                SCORE_TILE(a, ct);
                #pragma unroll
                for (int e = 0; e < 4; ++e) {
                    const bool in = a[e] > tv;
                    s += in ? a[e] : 0.f;
                    c += in ? 1.f : 0.f;
                }
            }
            s += __shfl_xor(s, 16); c += __shfl_xor(c, 16);
            s += __shfl_xor(s, 32); c += __shfl_xor(c, 32);
            tv = (s - 8.f) / c;
            const int C = (int)c;
            const bool done = (C == cprev);
            cprev = C;
            if (__all(done ? 1 : 0)) break;
        }
        tauF = tv;

        // dense chunked PV via this wave's own 8 KB LDS chunk as [16][128]
        float* p_lds = reinterpret_cast<float*>(&s_pack[widx][0][0]);
        float ofb[WROWS];
        #pragma unroll
        for (int r = 0; r < WROWS; ++r) ofb[r] = 0.f;
        for (int cc = 0; cc < 16; ++cc) {
            #pragma unroll
            for (int tt = 0; tt < 8; ++tt) {
                f32x4 a;
                SCORE_TILE(a, cc * 8 + tt);
                #pragma unroll
                for (int e = 0; e < 4; ++e)
                    p_lds[lm * 128 + tt * 16 + lk * 4 + e] = fmaxf(a[e] - tauF, 0.f);
            }
            for (int c2 = 0; c2 < 128; ++c2) {
                const float vv = Vb[(size_t)(cc * 128 + c2) * DHEAD + l];
                #pragma unroll
                for (int r = 0; r < WROWS; ++r)
                    ofb[r] += p_lds[r * 128 + c2] * vv;
            }
        }
        #pragma unroll
        for (int r = 0; r < WROWS; ++r)
            Of[(size_t)(row0w + r) * DHEAD + l] = ofb[r] * 0.125f;
    }
    #undef SCORE_TILE
}

extern "C" void kernel_launch(void* const* d_in, const int* in_sizes, int n_in,
                              void* d_out, int out_size, void* d_ws, size_t ws_size,
                              hipStream_t stream) {
    const float* q = (const float*)d_in[0];
    const float* k = (const float*)d_in[1];
    const float* v = (const float*)d_in[2];
    float* out = (float*)d_out;

    const int nElem = in_sizes[0];                    // B*H*S*D = 4194304
    const int BH    = nElem / (S_LEN * DHEAD);

    unsigned short* ks = (unsigned short*)d_ws;
    const int nfrag = nElem / 8;
    kswz_kernel<<<(nfrag + 255) / 256, 256, 0, stream>>>(k, (uint4*)ks, nfrag);

    const int grid = BH * (S_LEN / (WROWS * BWAVES)); // 1024 blocks
    spx_main<<<grid, 256, 0, stream>>>(q, ks, v, out);
}